// Round 6
// baseline (56.614 us; speedup 1.0000x reference)
//
#include <hip/hip_runtime.h>

#define N     384
#define BSZ   192
#define NM1   383
#define D     1024
#define DELTA 0.1f
#define NT2   12   // 32-row tiles per dimension in k_gram
#define NBLK  (NT2 * (NT2 + 1) / 2)   // 78 upper-tri tile pairs
#define BK    128  // K-chunk (8 chunks of 128)

typedef __attribute__((ext_vector_type(8))) short bf16x8;
typedef __attribute__((ext_vector_type(4))) float f32x4;

__device__ __forceinline__ const float* feat_row(const float* feats, int i) {
    // features laid out [192][2][1024]; logical row i of the [384,1024] concat
    int b = (i < BSZ) ? i : (i - BSZ);
    int s = (i < BSZ) ? 0 : 1;
    return feats + (size_t)(b * 2 + s) * D;
}

__device__ __forceinline__ unsigned short f2bf(float x) {  // RNE f32->bf16
    unsigned u = __builtin_bit_cast(unsigned, x);
    u = (u + 0x7FFFu + ((u >> 16) & 1u)) >> 16;
    return (unsigned short)u;
}
__device__ __forceinline__ float bf2f(unsigned short h) {
    unsigned u = ((unsigned)h) << 16;
    return __builtin_bit_cast(float, u);
}

// f32 -> (H, L) bf16 split + |f_i|^2; 4 rows/block (one per wave).
__global__ __launch_bounds__(256) void k_cvt(const float* __restrict__ feats,
                                             unsigned short* __restrict__ Hb,
                                             unsigned short* __restrict__ Lb,
                                             float* __restrict__ sq,
                                             unsigned* __restrict__ counter) {
    const int lane = threadIdx.x & 63, wv = threadIdx.x >> 6;
    const int i = blockIdx.x * 4 + wv;
    if (blockIdx.x == 0 && threadIdx.x == 0) *counter = 0u;
    const float4* f4 = (const float4*)feat_row(feats, i);
    float p = 0.f;
#pragma unroll
    for (int c = 0; c < 4; ++c) {
        float4 v = f4[lane + 64 * c];
        p = fmaf(v.x, v.x, p); p = fmaf(v.y, v.y, p);
        p = fmaf(v.z, v.z, p); p = fmaf(v.w, v.w, p);
        ushort4 h, l;
        h.x = f2bf(v.x); l.x = f2bf(v.x - bf2f(h.x));
        h.y = f2bf(v.y); l.y = f2bf(v.y - bf2f(h.y));
        h.z = f2bf(v.z); l.z = f2bf(v.z - bf2f(h.z));
        h.w = f2bf(v.w); l.w = f2bf(v.w - bf2f(h.w));
        const int e = 4 * (lane + 64 * c);
        *(ushort4*)(Hb + (size_t)i * D + e) = h;
        *(ushort4*)(Lb + (size_t)i * D + e) = l;
    }
#pragma unroll
    for (int off = 32; off; off >>= 1) p += __shfl_xor(p, off);
    if (lane == 0) sq[i] = p;
}

// Gram via MFMA, LDS-staged: G = H*H^T + H*L^T + L*H^T.
// 78 blocks = upper-tri 32x32 tiles; 4 waves = 4 quadrants, each 16x16 over
// full K. Coalesced global->reg->LDS staging, XOR swizzle (row&7)<<4,
// register double-buffer hides chunk c+1 loads under chunk c MFMAs.
__global__ __launch_bounds__(256) void k_gram(const unsigned short* __restrict__ Hb,
                                              const unsigned short* __restrict__ Lb,
                                              const float* __restrict__ sq,
                                              float* __restrict__ z) {
    int t = blockIdx.x, bi = 0;
    while (t >= NT2 - bi) { t -= NT2 - bi; ++bi; }
    const int bj = bi + t;
    const int i0 = bi * 32, j0 = bj * 32;
    const bool diag = (bi == bj);

    __shared__ unsigned short Ah[32 * BK], Al[32 * BK];
    __shared__ unsigned short Bh[32 * BK], Bl[32 * BK];

    const int tid  = threadIdx.x;
    const int lane = tid & 63, wv = tid >> 6;

    // staging map: seg s in [0,512): row = s>>4, colseg = s&15 (16B each);
    // this thread owns s = tid and s = tid+256.
    const int r0 = tid >> 4, r1 = (tid >> 4) + 16;
    const int cs = tid & 15;
    const size_t gA0 = (size_t)(i0 + r0) * D + cs * 8;
    const size_t gA1 = (size_t)(i0 + r1) * D + cs * 8;
    const size_t gB0 = (size_t)(j0 + r0) * D + cs * 8;
    const size_t gB1 = (size_t)(j0 + r1) * D + cs * 8;
    const int w0 = r0 * 256 + ((cs * 16) ^ ((r0 & 7) << 4));
    const int w1 = r1 * 256 + ((cs * 16) ^ ((r1 & 7) << 4));

    // fragment read addresses (quadrant qi=wv>>1, qj=wv&1)
    const int qi = wv >> 1, qj = wv & 1;
    const int ra = qi * 16 + (lane & 15);
    const int rb = qj * 16 + (lane & 15);
    const int cb = (lane >> 4) * 16;

    uint4 rg[2][8];
    // preload chunk 0
#define LOADC(buf, kc) do { \
        rg[buf][0] = *(const uint4*)(Hb + gA0 + (kc) * BK); \
        rg[buf][1] = *(const uint4*)(Hb + gA1 + (kc) * BK); \
        rg[buf][2] = *(const uint4*)(Lb + gA0 + (kc) * BK); \
        rg[buf][3] = *(const uint4*)(Lb + gA1 + (kc) * BK); \
        if (!diag) { \
            rg[buf][4] = *(const uint4*)(Hb + gB0 + (kc) * BK); \
            rg[buf][5] = *(const uint4*)(Hb + gB1 + (kc) * BK); \
            rg[buf][6] = *(const uint4*)(Lb + gB0 + (kc) * BK); \
            rg[buf][7] = *(const uint4*)(Lb + gB1 + (kc) * BK); \
        } \
    } while (0)
    LOADC(0, 0);

    f32x4 acc = {0.f, 0.f, 0.f, 0.f};
    const unsigned short* Bhp = diag ? Ah : Bh;
    const unsigned short* Blp = diag ? Al : Bl;

#pragma unroll
    for (int c = 0; c < 8; ++c) {
        const int cur = c & 1;
        __syncthreads();   // previous compute done; LDS writable
        *(uint4*)((char*)Ah + w0) = rg[cur][0];
        *(uint4*)((char*)Ah + w1) = rg[cur][1];
        *(uint4*)((char*)Al + w0) = rg[cur][2];
        *(uint4*)((char*)Al + w1) = rg[cur][3];
        if (!diag) {
            *(uint4*)((char*)Bh + w0) = rg[cur][4];
            *(uint4*)((char*)Bh + w1) = rg[cur][5];
            *(uint4*)((char*)Bl + w0) = rg[cur][6];
            *(uint4*)((char*)Bl + w1) = rg[cur][7];
        }
        if (c < 7) LOADC(cur ^ 1, c + 1);
        __syncthreads();   // LDS ready
#pragma unroll
        for (int kk = 0; kk < 4; ++kk) {
            const int ca = kk * 64 + cb;
            bf16x8 aH = *(const bf16x8*)((const char*)Ah + ra * 256 + (ca ^ ((ra & 7) << 4)));
            bf16x8 aL = *(const bf16x8*)((const char*)Al + ra * 256 + (ca ^ ((ra & 7) << 4)));
            bf16x8 bH = *(const bf16x8*)((const char*)Bhp + rb * 256 + (ca ^ ((rb & 7) << 4)));
            bf16x8 bL = *(const bf16x8*)((const char*)Blp + rb * 256 + (ca ^ ((rb & 7) << 4)));
            acc = __builtin_amdgcn_mfma_f32_16x16x32_bf16(aH, bH, acc, 0, 0, 0);
            acc = __builtin_amdgcn_mfma_f32_16x16x32_bf16(aH, bL, acc, 0, 0, 0);
            acc = __builtin_amdgcn_mfma_f32_16x16x32_bf16(aL, bH, acc, 0, 0, 0);
        }
    }
#undef LOADC

    // C/D layout (verified): col = lane&15, row = (lane>>4)*4 + reg
    const int jj = j0 + qj * 16 + (lane & 15);
    const int rbase = i0 + qi * 16 + ((lane >> 4) << 2);
#pragma unroll
    for (int r = 0; r < 4; ++r) {
        const int ii = rbase + r;
        if (!diag || ii < jj) {
            if (ii != jj) {
                float sd = fmaxf(sq[ii] + sq[jj] - 2.f * acc[r], 0.f);
                float v  = sqrtf(sd);
                z[ii * NM1 + (jj < ii ? jj : jj - 1)] = v;
                z[jj * NM1 + (ii < jj ? ii : ii - 1)] = v;
            }
        }
    }
}

// One block per row: LDS counting sort by y_abs, all-pairs quadratic term,
// sparse same-y correction, per-row partial; last block reduces -> out.
__global__ __launch_bounds__(256) void k_main(const float* __restrict__ z,
                                              const int* __restrict__ labels,
                                              float* __restrict__ partial,
                                              unsigned* __restrict__ counter,
                                              float* __restrict__ out) {
    const int i = blockIdx.x, tid = threadIdx.x;
    __shared__ float zbuf[NM1];
    __shared__ unsigned char yrow[NM1];
    __shared__ int cnt[64], startv[64], cur[64];
    __shared__ float rankd[64];
    __shared__ float2 zr[N];      // sorted (z, rank*DELTA); slot 383 = pad
    __shared__ unsigned grs[N];   // lo | hi<<9 per sorted slot
    __shared__ int lastFlag;

    if (tid < 64) cnt[tid] = 0;
    for (int k = tid; k < NM1; k += 256) zbuf[k] = z[i * NM1 + k];
    __syncthreads();
    const int li = labels[(i < BSZ) ? i : (i - BSZ)];
    for (int k = tid; k < NM1; k += 256) {
        int col = k + (k >= i ? 1 : 0);
        int ya  = abs(li - labels[(col < BSZ) ? col : (col - BSZ)]);
        yrow[k] = (unsigned char)ya;
        atomicAdd(&cnt[ya], 1);
    }
    __syncthreads();
    if (tid == 0) {
        int c = 0, r = 0;
        for (int v = 0; v < 64; ++v) {
            startv[v] = c;
            rankd[v]  = (float)r * DELTA;
            if (cnt[v] > 0) ++r;
            c += cnt[v];
        }
    }
    __syncthreads();
    if (tid < 64) cur[tid] = startv[tid];
    __syncthreads();
    for (int k = tid; k < NM1; k += 256) {
        int ya  = yrow[k];
        int pos = atomicAdd(&cur[ya], 1);
        zr[pos]  = make_float2(zbuf[k], rankd[ya]);
        grs[pos] = (unsigned)startv[ya] | ((unsigned)(startv[ya] + cnt[ya]) << 9);
    }
    if (tid == 0) zr[NM1] = make_float2(0.f, 0.f);
    __syncthreads();

    // all-pairs term: (|zk-zj| - |rk-rj|)^2, 2 k-slots per thread
    const float zk0 = zr[tid].x, rk0 = zr[tid].y;
    const bool  v1  = (tid + 256 < NM1);
    const int   k1  = v1 ? tid + 256 : NM1;   // pad slot; s1 masked below
    const float zk1 = zr[k1].x, rk1 = zr[k1].y;

    float s0 = 0.f, s1 = 0.f;
#define PAIRQ(q) do { \
        float t0 = fabsf(zk0 - (q).x) - fabsf(rk0 - (q).y); s0 = fmaf(t0, t0, s0); \
        float t1 = fabsf(zk1 - (q).x) - fabsf(rk1 - (q).y); s1 = fmaf(t1, t1, s1); \
    } while (0)
    int j = 0;
    for (; j + 4 <= NM1; j += 4) {
        float2 q0 = zr[j], q1 = zr[j+1], q2 = zr[j+2], q3 = zr[j+3];
        PAIRQ(q0); PAIRQ(q1); PAIRQ(q2); PAIRQ(q3);
    }
    for (; j < NM1; ++j) { float2 q = zr[j]; PAIRQ(q); }
#undef PAIRQ
    if (!v1) s1 = 0.f;

    // correction over same-y pairs: a*sigmoid(a-DELTA) - a^2 over [lo,hi)
    float cs = 0.f;
    for (int jj = tid; jj < NM1; jj += 256) {
        const float    zj = zr[jj].x;
        const unsigned g  = grs[jj];
        const int lo = g & 0x1FF;
        const int hi = (g >> 9) & 0x1FF;
        for (int k = lo; k < hi; ++k) {
            float a = fabsf(zr[k].x - zj);
            cs += a * __builtin_amdgcn_rcpf(1.f + __expf(DELTA - a)) - a * a;
        }
    }

    float sum = s0 + s1 + cs;
#pragma unroll
    for (int off = 32; off; off >>= 1) sum += __shfl_xor(sum, off);
    __shared__ float part[4];
    if ((tid & 63) == 0) part[tid >> 6] = sum;
    __syncthreads();
    if (tid == 0) {
        partial[i] = part[0] + part[1] + part[2] + part[3];
        __threadfence();
        unsigned old = atomicAdd(counter, 1u);
        lastFlag = (old == N - 1);
    }
    __syncthreads();

    if (lastFlag) {
        // atomic reads bypass any stale per-XCD L2 lines
        double s = 0.0;
        for (int t2 = tid; t2 < N; t2 += 256) s += (double)atomicAdd(&partial[t2], 0.f);
#pragma unroll
        for (int off = 32; off; off >>= 1) s += __shfl_xor(s, off);
        __shared__ double dp[4];
        if ((tid & 63) == 0) dp[tid >> 6] = s;
        __syncthreads();
        if (tid == 0) {
            const double M = (double)N * (double)NM1 * (double)NM1;
            out[0] = (float)((dp[0] + dp[1] + dp[2] + dp[3]) / M);
        }
    }
}

extern "C" void kernel_launch(void* const* d_in, const int* in_sizes, int n_in,
                              void* d_out, int out_size, void* d_ws, size_t ws_size,
                              hipStream_t stream) {
    const float* feats  = (const float*)d_in[0];
    const int*   labels = (const int*)d_in[1];
    float*       out    = (float*)d_out;

    // ws layout (~2.2 MB total):
    char* ws = (char*)d_ws;
    float*          sq      = (float*)ws;                          // 1536 B
    unsigned*       counter = (unsigned*)(ws + 2048);              // 4 B
    float*          partial = (float*)(ws + 4096);                 // 1536 B
    unsigned short* Hb      = (unsigned short*)(ws + 16384);       // 768 KiB
    unsigned short* Lb      = (unsigned short*)(ws + 16384 + 786432);        // 768 KiB
    float*          z       = (float*)(ws + 16384 + 2 * 786432);   // 588 KiB

    k_cvt <<<N / 4, 256, 0, stream>>>(feats, Hb, Lb, sq, counter);
    k_gram<<<NBLK, 256, 0, stream>>>(Hb, Lb, sq, z);
    k_main<<<N, 256, 0, stream>>>(z, labels, partial, counter, out);
}